// Round 10
// baseline (385.812 us; speedup 1.0000x reference)
//
#include <hip/hip_runtime.h>

typedef unsigned short u16;
typedef unsigned int   u32;
typedef __attribute__((ext_vector_type(8))) short bf16x8;
typedef __attribute__((ext_vector_type(4))) float f32x4;

#define NB 131072               // batch rows
#define LN_EPS 1e-5f

// Native RNE fp32->bf16 (compiler emits packed cvt on gfx950)
__device__ __forceinline__ u16 f2b(float f){
  union { __bf16 h; u16 u; } c; c.h = (__bf16)f; return c.u;
}
__device__ __forceinline__ u32 pk2(float a, float b){
  return (u32)f2b(a) | ((u32)f2b(b) << 16);
}
__device__ __forceinline__ float upk(u32 pr, int hi){
  union { u32 u; float f; } c; c.u = hi ? (pr & 0xFFFF0000u) : (pr << 16); return c.f;
}
// feature-sum across quads (features live in-thread + lane bits 4,5)
__device__ __forceinline__ float qsum(float x){
  x += __shfl_xor(x, 16);
  x += __shfl_xor(x, 32);
  return x;
}
// 8 consecutive fp32 -> bf16x8 fragment chunk
__device__ __forceinline__ bf16x8 cvt8(const float* __restrict__ s){
  f32x4 x0 = *(const f32x4*)s;
  f32x4 x1 = *(const f32x4*)(s + 4);
  bf16x8 r;
  r[0]=(short)f2b(x0[0]); r[1]=(short)f2b(x0[1]);
  r[2]=(short)f2b(x0[2]); r[3]=(short)f2b(x0[3]);
  r[4]=(short)f2b(x1[0]); r[5]=(short)f2b(x1[1]);
  r[6]=(short)f2b(x1[2]); r[7]=(short)f2b(x1[3]);
  return r;
}

// async global->LDS, 16 B per lane (dest = uniform base + lane*16, src per-lane)
__device__ __forceinline__ void glds16(const u16* g, u16* l){
  __builtin_amdgcn_global_load_lds(
      (const __attribute__((address_space(1))) void*)g,
      (__attribute__((address_space(3))) void*)l, 16, 0, 0);
}
// Stage one 128x128 bf16 weight matrix (32 KiB, fragment-order = lane-linear) into LDS.
// Completion = next __syncthreads() (its vmcnt(0) drain is the staging wait).
__device__ __forceinline__ void stageB(const u16* __restrict__ packB, int m,
                                       u16* __restrict__ bst, int wave, int lane){
  const u16* src = packB + m*16384 + wave*512 + lane*8;
  u16*       dst = bst   + wave*512;          // wave-uniform; HW adds lane*16B
  #pragma unroll
  for (int k = 0; k < 8; k++)
    glds16(src + k*2048, dst + k*2048);
}

// SWAPPED 16x128 @ 128x128 GEMM: weight frags (LDS) as A-operand, activation
// frags (regs) as B-operand -> C transposed: batch row = l15,
// feature = mt*16 + quad*4 + r.
__device__ __forceinline__ void gemm16s(const bf16x8 x[4], const u16* __restrict__ Blds,
                                        int lane, f32x4 C[8]){
  const bf16x8* Wf = (const bf16x8*)Blds;
  #pragma unroll
  for (int mt = 0; mt < 8; mt++){
    f32x4 c = {0.f, 0.f, 0.f, 0.f};
    #pragma unroll
    for (int kt = 0; kt < 4; kt++){
      bf16x8 wfrag = Wf[(mt*4 + kt)*64 + lane];   // ds_read_b128, contiguous
      c = __builtin_amdgcn_mfma_f32_16x16x32_bf16(wfrag, x[kt], c, 0, 0, 0);
    }
    C[mt] = c;
  }
}

// In-register C->B-fragment exchange (replaces the LDS exch buffer).
// Dest (l15,q) needs, for kt: C[mt] of lanes sl0=2(q&1)*16+l15 and sl0+16,
// mt = 2kt + (q>>1). pk[mt] = bf16-packed C[mt] (2 u32). Register index must
// be wave-uniform -> pull both parities, select by odd=(q>>1).
// ds_bpermute: broadcast-2 source pattern, conflict-free; no barrier needed.
__device__ __forceinline__ void pulls(const u32 pk[8][2], int sl0, int sl1,
                                      bool odd, bf16x8 x[4]){
  #pragma unroll
  for (int kt = 0; kt < 4; kt++){
    union { u32 u[4]; bf16x8 v; } r;
    u32 e0 = (u32)__shfl((int)pk[2*kt  ][0], sl0, 64);
    u32 e1 = (u32)__shfl((int)pk[2*kt  ][1], sl0, 64);
    u32 e2 = (u32)__shfl((int)pk[2*kt  ][0], sl1, 64);
    u32 e3 = (u32)__shfl((int)pk[2*kt  ][1], sl1, 64);
    u32 o0 = (u32)__shfl((int)pk[2*kt+1][0], sl0, 64);
    u32 o1 = (u32)__shfl((int)pk[2*kt+1][1], sl0, 64);
    u32 o2 = (u32)__shfl((int)pk[2*kt+1][0], sl1, 64);
    u32 o3 = (u32)__shfl((int)pk[2*kt+1][1], sl1, 64);
    r.u[0] = odd ? o0 : e0;
    r.u[1] = odd ? o1 : e1;
    r.u[2] = odd ? o2 : e2;
    r.u[3] = odd ? o3 : e3;
    x[kt] = r.v;
  }
}

// ---------------- prep: pack weights (fp32 -> bf16, gamma FOLDED) + fused biases ----
// packB unchanged (verified): B-fragment layout doubles as A-fragment of W/W^T.
// vecs (768 fp32): cb0 = b_in + se0 | cb1..3 = b'_{i-1} + se_i | cb4 = b'_3 | b_out
// where b'_i = bl_i + Wl_i @ beta_i, se_i = sin(t*fw_i + fb_i).
__global__ void prep_kernel(const float* __restrict__ t,   const float* __restrict__ W_in,
                            const float* __restrict__ b_in,const float* __restrict__ fw,
                            const float* __restrict__ fb,  const float* __restrict__ gamma,
                            const float* __restrict__ beta,const float* __restrict__ Wl,
                            const float* __restrict__ bl,  const float* __restrict__ W_out,
                            const float* __restrict__ b_out,
                            u16* __restrict__ packB, float* __restrict__ vecs)
{
  int bid = blockIdx.x, tid = threadIdx.x;
  if (bid < 768){
    int e    = bid*256 + tid;       // 0..196607
    int m    = e >> 14;             // matrix 0..11
    int r    = e & 16383;
    int fi   = r >> 9;              // nt*4+kt
    int lane = (r >> 3) & 63;
    int j    = r & 7;
    int nt = fi >> 2, kt = fi & 3;
    int k = kt*32 + (lane >> 4)*8 + j;
    int n = nt*16 + (lane & 15);
    const float* src; bool tr;
    if      (m == 0){ src = W_in;              tr = true;  }
    else if (m <= 4){ src = Wl + (m-1)*16384;  tr = true;  }
    else if (m == 5){ src = W_out;             tr = true;  }
    else if (m == 6){ src = W_out;             tr = false; }
    else if (m <=10){ src = Wl + (m-7)*16384;  tr = false; }
    else            { src = W_in;              tr = false; }
    float v = tr ? src[n*128 + k] : src[k*128 + n];
    if      (m >= 1 && m <= 4)  v *= gamma[(m-1)*128 + k];   // fwd: scale contraction dim
    else if (m >= 7 && m <= 10) v *= gamma[(m-7)*128 + n];   // bwd: scale output dim
    packB[e] = f2b(v);
  } else {
    int gid = (bid - 768)*256 + tid;   // 0..767
    int vec = gid >> 7, o = gid & 127;
    float v;
    if (vec == 0){
      v = b_in[o] + sinf(t[0]*fw[o] + fb[o]);
    } else if (vec <= 3){
      int i = vec - 1;
      const float* Wr = Wl + i*16384 + o*128;
      const float* be = beta + i*128;
      float acc = bl[i*128 + o];
      for (int k2 = 0; k2 < 128; k2++) acc += be[k2]*Wr[k2];
      v = acc + sinf(t[0]*fw[vec*128 + o] + fb[vec*128 + o]);
    } else if (vec == 4){
      const float* Wr = Wl + 3*16384 + o*128;
      const float* be = beta + 3*128;
      float acc = bl[3*128 + o];
      for (int k2 = 0; k2 < 128; k2++) acc += be[k2]*Wr[k2];
      v = acc;
    } else {
      v = b_out[o];
    }
    vecs[gid] = v;
  }
}

// ---------------- fused forward + VJP ----------------
// Round 13: LDS exchange -> in-register bpermute exchange (pulls); sin embed
// folded into GEMM biases (cb). LDS: bstage 32768 + sv 3072 = 35840 B
// (was 54272) -> LDS now allows 4 blocks/CU; registers (~156 unified <= 170)
// give 3 waves/SIMD. No launch-bounds cap (r4/r7 lesson: cap => spill).
// Barrier schedule identical to r9 (A: bstage WAR; B: staging drain).
// Spill tripwire: hbm_bytes ~2.1e8. Occupancy target: ~30%.
__global__ __launch_bounds__(256, 2)
void fused_vf(const float* __restrict__ p, const float* __restrict__ w,
              const u16* __restrict__ packB, const float* __restrict__ vecs,
              float* __restrict__ dp_out, float* __restrict__ dw_out)
{
  __shared__ __align__(16) u16  bstage[16384];
  __shared__ __align__(16) float sv[768];

  const int tid  = threadIdx.x;
  const int wave = tid >> 6, lane = tid & 63;
  const int l15  = lane & 15, quad = lane >> 4;
  const int sl0  = ((quad & 1) << 5) + l15;   // source lane for low half
  const int sl1  = sl0 + 16;                  // source lane for high half
  const bool odd = (quad >> 1) != 0;          // mt parity select

  stageB(packB, 0, bstage, wave, lane);          // B0 in flight
  for (int idx = tid; idx < 768; idx += 256) sv[idx] = vecs[idx];
  const float* sCb   = sv;          // [5][128] fused biases
  const float* sBout = sv + 640;    // [128]

  const long rowBase = (long)blockIdx.x * 64 + wave * 16;

  // backward checkpoints
  u32   sp_ck[4][8][2];  // sp bf16-packed along r (feature) dim (64 regs)
  float mus[4];          // LN mean per layer (scalar per batch row)
  float invs[4];         // LN inv-std

  bf16x8 x[4];
  f32x4  C[8];

  // ---- forward: h0^T = W_in (.) p ----
  {
    const float* pr = p + (size_t)(rowBase + l15)*128 + quad*8;
    #pragma unroll
    for (int kt = 0; kt < 4; kt++) x[kt] = cvt8(pr + kt*32);
  }
  __syncthreads();                               // sv + B0 staged
  gemm16s(x, bstage, lane, C);
  #pragma unroll
  for (int mt = 0; mt < 8; mt++)
    C[mt] += *(const f32x4*)(sCb + mt*16 + quad*4);      // cb0 = b_in + se0

  // ---- forward layers ----
  #pragma unroll
  for (int i = 0; i < 4; i++){
    __syncthreads();                             // A: bstage reads done
    stageB(packB, 1+i, bstage, wave, lane);      // next W hides under compute
    float sum = 0.f, ssq = 0.f;
    #pragma unroll
    for (int mt = 0; mt < 8; mt++){
      #pragma unroll
      for (int r = 0; r < 4; r++){
        float a_ = C[mt][r];                      // a_i (se already folded in)
        float e  = __expf(-fabsf(a_));
        float sp = fmaxf(a_, 0.0f) + __logf(1.0f + e);  // softplus
        u16 sb = f2b(sp);                         // checkpoint sp
        if (r & 1) sp_ck[i][mt][r>>1] |= ((u32)sb) << 16; else sp_ck[i][mt][r>>1] = sb;
        sum += sp; ssq += sp*sp;
        C[mt][r] = sp;
      }
    }
    float m1 = qsum(sum) * (1.0f/128.0f);
    float m2 = qsum(ssq) * (1.0f/128.0f);
    float inv = rsqrtf(fmaxf(m2 - m1*m1, 0.0f) + LN_EPS);
    mus[i] = m1; invs[i] = inv;
    {
      u32 pk[8][2];
      #pragma unroll
      for (int mt = 0; mt < 8; mt++){
        pk[mt][0] = pk2((C[mt][0]-m1)*inv, (C[mt][1]-m1)*inv);
        pk[mt][1] = pk2((C[mt][2]-m1)*inv, (C[mt][3]-m1)*inv);
      }
      pulls(pk, sl0, sl1, odd, x);               // in-register exchange
    }
    __syncthreads();                             // B: staging ready
    gemm16s(x, bstage, lane, C);
    #pragma unroll
    for (int mt = 0; mt < 8; mt++)
      C[mt] += *(const f32x4*)(sCb + (i+1)*128 + mt*16 + quad*4);  // b'_i (+ se_{i+1})
  }

  // ---- forward head: dp^T = W_out (.) h4 ----
  __syncthreads();                               // A
  stageB(packB, 5, bstage, wave, lane);
  {
    u32 pk[8][2];
    #pragma unroll
    for (int mt = 0; mt < 8; mt++){
      pk[mt][0] = pk2(C[mt][0], C[mt][1]);
      pk[mt][1] = pk2(C[mt][2], C[mt][3]);
    }
    pulls(pk, sl0, sl1, odd, x);
  }
  __syncthreads();                               // B
  gemm16s(x, bstage, lane, C);
  {
    float* gp = dp_out + (size_t)(rowBase + l15)*128;
    #pragma unroll
    for (int mt = 0; mt < 8; mt++){
      f32x4 o = C[mt] + *(const f32x4*)(sBout + mt*16 + quad*4);
      *(f32x4*)(gp + mt*16 + quad*4) = o;         // global_store_dwordx4
    }
  }

  // ---- backward: g_h4^T = W_out^T (.) w ----
  __syncthreads();                               // A
  stageB(packB, 6, bstage, wave, lane);
  {
    const float* wr = w + (size_t)(rowBase + l15)*128 + quad*8;
    #pragma unroll
    for (int kt = 0; kt < 4; kt++) x[kt] = cvt8(wr + kt*32);
  }
  __syncthreads();                               // B (w-load latency covered staging)
  gemm16s(x, bstage, lane, C);
  __syncthreads();                               // A
  stageB(packB, 10, bstage, wave, lane);         // first bwd-layer W

  #pragma unroll
  for (int ii = 0; ii < 4; ii++){
    const int i = 3 - ii;
    {
      u32 pk[8][2];
      #pragma unroll
      for (int mt = 0; mt < 8; mt++){
        pk[mt][0] = pk2(C[mt][0], C[mt][1]);
        pk[mt][1] = pk2(C[mt][2], C[mt][3]);
      }
      pulls(pk, sl0, sl1, odd, x);
    }
    __syncthreads();                             // B: staging ready
    gemm16s(x, bstage, lane, C);                 // g_xh^T = (Wl*gamma)^T (.) g
    __syncthreads();                             // A: bstage reads done
    stageB(packB, (ii < 3) ? (7 + (2 - ii)) : 11, bstage, wave, lane);
    // LN backward from sp-checkpoint (scalar stats per batch row)
    float s1 = 0.f, s2 = 0.f;
    #pragma unroll
    for (int mt = 0; mt < 8; mt++)
      #pragma unroll
      for (int r = 0; r < 4; r++){
        float sp = upk(sp_ck[i][mt][r>>1], r & 1);
        float xh = (sp - mus[i]) * invs[i];
        float gx = C[mt][r];                      // g_xhat (gamma folded)
        s1 += gx; s2 += gx * xh;
      }
    float m1 = qsum(s1) * (1.0f/128.0f);
    float m2 = qsum(s2) * (1.0f/128.0f);
    #pragma unroll
    for (int mt = 0; mt < 8; mt++)
      #pragma unroll
      for (int r = 0; r < 4; r++){
        float sp = upk(sp_ck[i][mt][r>>1], r & 1);
        float xh = (sp - mus[i]) * invs[i];
        float sg = 1.0f - __expf(-sp);            // sigmoid(a) = 1 - exp(-softplus(a))
        float gu = invs[i] * (C[mt][r] - m1 - xh * m2);
        C[mt][r] = gu * sg;                       // g_a == g_h(prev layer)
      }
  }

  // ---- backward tail: g_p^T = W_in^T (.) g ; dw = -g_p ----
  {
    u32 pk[8][2];
    #pragma unroll
    for (int mt = 0; mt < 8; mt++){
      pk[mt][0] = pk2(C[mt][0], C[mt][1]);
      pk[mt][1] = pk2(C[mt][2], C[mt][3]);
    }
    pulls(pk, sl0, sl1, odd, x);
  }
  __syncthreads();                               // B: staging(11) ready
  gemm16s(x, bstage, lane, C);
  {
    float* gp = dw_out + (size_t)(rowBase + l15)*128;
    #pragma unroll
    for (int mt = 0; mt < 8; mt++){
      f32x4 o = -C[mt];
      *(f32x4*)(gp + mt*16 + quad*4) = o;
    }
  }
}

extern "C" void kernel_launch(void* const* d_in, const int* in_sizes, int n_in,
                              void* d_out, int out_size, void* d_ws, size_t ws_size,
                              hipStream_t stream)
{
  const float* t     = (const float*)d_in[0];
  const float* p     = (const float*)d_in[1];
  const float* w     = (const float*)d_in[2];
  const float* W_in  = (const float*)d_in[3];
  const float* b_in  = (const float*)d_in[4];
  const float* fw    = (const float*)d_in[5];
  const float* fb    = (const float*)d_in[6];
  const float* gamma = (const float*)d_in[7];
  const float* beta  = (const float*)d_in[8];
  const float* Wl    = (const float*)d_in[9];
  const float* bl    = (const float*)d_in[10];
  const float* W_out = (const float*)d_in[11];
  const float* b_out = (const float*)d_in[12];

  u16*   packB = (u16*)d_ws;                           // 12*16384 bf16 = 384 KiB
  float* vecs  = (float*)((char*)d_ws + 12*16384*2);   // 768 fp32

  prep_kernel<<<771, 256, 0, stream>>>(t, W_in, b_in, fw, fb, gamma, beta,
                                       Wl, bl, W_out, b_out, packB, vecs);

  float* dp = (float*)d_out;
  float* dw = (float*)d_out + (size_t)NB * 128;
  fused_vf<<<NB/64, 256, 0, stream>>>(p, w, packB, vecs, dp, dw);
}